// Round 5
// baseline (296.001 us; speedup 1.0000x reference)
//
#include <hip/hip_runtime.h>
#include <hip/hip_bf16.h>
#include <cstddef>
#include <cstdint>

#define Bv 4
#define Nv 1024
#define DM 512
#define Hh 8
#define DHv 64
#define TOKc 4096

typedef __attribute__((ext_vector_type(4))) float f32x4;
typedef __attribute__((ext_vector_type(8))) short s16x8;

__device__ __forceinline__ uint32_t f2bf_bits(float f) {
    uint32_t x = __float_as_uint(f);
    return (x + 0x7FFFu + ((x >> 16) & 1u)) >> 16;
}
__device__ __forceinline__ short f2bf(float f) { return (short)f2bf_bits(f); }
__device__ __forceinline__ float bf2f(short s) {
    return __uint_as_float(((uint32_t)(uint16_t)s) << 16);
}

__device__ __forceinline__ void g2lds16(const void* g, void* l) {
    __builtin_amdgcn_global_load_lds(
        (const __attribute__((address_space(1))) void*)g,
        (__attribute__((address_space(3))) void*)l, 16, 0, 0);
}

// ---------------------------------------------------------------------------
// all 4 weight tensors -> bf16, one launch
// ---------------------------------------------------------------------------
__global__ __launch_bounds__(256) void conv_all(
    const float* __restrict__ W0, const float* __restrict__ W1,
    const float* __restrict__ W2, const float* __restrict__ W3,
    short* __restrict__ D0, short* __restrict__ D1,
    short* __restrict__ D2, short* __restrict__ D3)
{
    int bid = blockIdx.x;
    const float* s; short* d; int base;
    if (bid < 768)       { s = W0; d = D0; base = bid * 1024; }
    else if (bid < 1024) { s = W1; d = D1; base = (bid - 768) * 1024; }
    else if (bid < 2048) { s = W2; d = D2; base = (bid - 1024) * 1024; }
    else                 { s = W3; d = D3; base = (bid - 2048) * 1024; }
    int i = base + threadIdx.x * 4;
    float4 v = *(const float4*)&s[i];
    short4 o = { f2bf(v.x), f2bf(v.y), f2bf(v.z), f2bf(v.w) };
    *(short4*)&d[i] = o;
}

// ---------------------------------------------------------------------------
// pack bias = new_mask - gamma*D (lo bf16) and mask (hi bf16) into u32
// ---------------------------------------------------------------------------
__global__ __launch_bounds__(256) void prep_bm(
    const float* __restrict__ Dm, const float* __restrict__ nm,
    const float* __restrict__ mk, const float* __restrict__ gamma,
    uint32_t* __restrict__ out)
{
    int i = (blockIdx.x * 256 + threadIdx.x) * 4;
    float g = gamma[0];
    float4 d = *(const float4*)&Dm[i];
    float4 n = *(const float4*)&nm[i];
    float4 m = *(const float4*)&mk[i];
    uint4 o;
    o.x = f2bf_bits(n.x - g * d.x) | (f2bf_bits(m.x) << 16);
    o.y = f2bf_bits(n.y - g * d.y) | (f2bf_bits(m.y) << 16);
    o.z = f2bf_bits(n.z - g * d.z) | (f2bf_bits(m.z) << 16);
    o.w = f2bf_bits(n.w - g * d.w) | (f2bf_bits(m.w) << 16);
    *(uint4*)&out[i] = o;
}

// ---------------------------------------------------------------------------
// LayerNorm -> bf16 out
// ---------------------------------------------------------------------------
__global__ __launch_bounds__(256) void ln_kernel(
    const float* __restrict__ X, const float* __restrict__ g,
    const float* __restrict__ bb, short* __restrict__ Y)
{
    __shared__ float red[8];
    int row = blockIdx.x, tid = threadIdx.x;
    const float* x = X + (size_t)row * DM;
    float v0 = x[tid], v1 = x[tid + 256];
    float s = v0 + v1, ss = v0 * v0 + v1 * v1;
#pragma unroll
    for (int o = 32; o > 0; o >>= 1) {
        s += __shfl_xor(s, o);
        ss += __shfl_xor(ss, o);
    }
    int lane = tid & 63, wid = tid >> 6;
    if (lane == 0) { red[wid] = s; red[4 + wid] = ss; }
    __syncthreads();
    float S = red[0] + red[1] + red[2] + red[3];
    float SS = red[4] + red[5] + red[6] + red[7];
    float mean = S * (1.f / DM);
    float var = SS * (1.f / DM) - mean * mean;
    float rstd = rsqrtf(var + 1e-5f);
    short* y = Y + (size_t)row * DM;
    y[tid]       = f2bf((v0 - mean) * rstd * g[tid]       + bb[tid]);
    y[tid + 256] = f2bf((v1 - mean) * rstd * g[tid + 256] + bb[tid + 256]);
}

// ---------------------------------------------------------------------------
// bf16 MFMA NT GEMM, BK=64 (two proven [rows][32] LDS buffers per matrix,
// halved barrier count vs R4). Tile BM x BN, 4 waves in 2x2.
// ---------------------------------------------------------------------------
template <int EPI, int BM, int BN>
__global__ __launch_bounds__(256) void gemm_bf16(
    const short* __restrict__ A, const short* __restrict__ Bw,
    const float* __restrict__ bias, const float* __restrict__ resid,
    void* __restrict__ C0, short* __restrict__ C2, short* __restrict__ C3,
    int M, int N, int Ks, int Kst)
{
    constexpr int FI = BM / 32, FJ = BN / 32;
    __shared__ short As0[BM * 32];
    __shared__ short As1[BM * 32];
    __shared__ short Bs0[BN * 32];
    __shared__ short Bs1[BN * 32];
    int tid = threadIdx.x;
    int lane = tid & 63, wave = tid >> 6;
    int bm = blockIdx.y * BM, bn = blockIdx.x * BN;
    int wm = (wave >> 1) * (BM / 2), wn = (wave & 1) * (BN / 2);
    int n_lo = lane & 15, quad = lane >> 4;

    f32x4 acc[FI][FJ] = {};

    int koff = (EPI == 4) ? blockIdx.z * Ks : 0;
    int lrow = lane >> 2, lchunk = (lane & 3) * 8;
    const short* Ag = A + (size_t)(bm + wave * (BM / 4) + lrow) * Kst + koff + lchunk;
    const short* Bg = Bw + (size_t)(bn + wave * (BN / 4) + lrow) * Kst + koff + lchunk;

    for (int k0 = 0; k0 < Ks; k0 += 64) {
        __syncthreads();
#pragma unroll
        for (int r = 0; r < BM / 64; r++) {
            g2lds16(Ag + (size_t)r * 16 * Kst + k0,      &As0[(wave * (BM / 4) + r * 16) * 32]);
            g2lds16(Ag + (size_t)r * 16 * Kst + k0 + 32, &As1[(wave * (BM / 4) + r * 16) * 32]);
        }
#pragma unroll
        for (int r = 0; r < BN / 64; r++) {
            g2lds16(Bg + (size_t)r * 16 * Kst + k0,      &Bs0[(wave * (BN / 4) + r * 16) * 32]);
            g2lds16(Bg + (size_t)r * 16 * Kst + k0 + 32, &Bs1[(wave * (BN / 4) + r * 16) * 32]);
        }
        __syncthreads();
        s16x8 af0[FI], af1[FI], bf0[FJ], bf1[FJ];
#pragma unroll
        for (int i = 0; i < FI; i++) {
            af0[i] = *(const s16x8*)&As0[(wm + i * 16 + n_lo) * 32 + quad * 8];
            af1[i] = *(const s16x8*)&As1[(wm + i * 16 + n_lo) * 32 + quad * 8];
        }
#pragma unroll
        for (int j = 0; j < FJ; j++) {
            bf0[j] = *(const s16x8*)&Bs0[(wn + j * 16 + n_lo) * 32 + quad * 8];
            bf1[j] = *(const s16x8*)&Bs1[(wn + j * 16 + n_lo) * 32 + quad * 8];
        }
#pragma unroll
        for (int i = 0; i < FI; i++)
#pragma unroll
            for (int j = 0; j < FJ; j++)
                acc[i][j] = __builtin_amdgcn_mfma_f32_16x16x32_bf16(
                    af0[i], bf0[j], acc[i][j], 0, 0, 0);
#pragma unroll
        for (int i = 0; i < FI; i++)
#pragma unroll
            for (int j = 0; j < FJ; j++)
                acc[i][j] = __builtin_amdgcn_mfma_f32_16x16x32_bf16(
                    af1[i], bf1[j], acc[i][j], 0, 0, 0);
    }

#pragma unroll
    for (int i = 0; i < FI; i++) {
#pragma unroll
        for (int j = 0; j < FJ; j++) {
            int col = bn + wn + j * 16 + n_lo;
#pragma unroll
            for (int r = 0; r < 4; r++) {
                int m = bm + wm + i * 16 + quad * 4 + r;
                float v = acc[i][j][r];
                if (EPI == 0) {
                    v += bias[col];
                    int hh = col / 192;
                    int rr = col - hh * 192;
                    int part = rr >> 6, dd = rr & 63;
                    int bI = m >> 10, nI = m & 1023;
                    if (part == 0)
                        ((short*)C0)[((size_t)((bI * Hh + hh) * DHv + dd)) * Nv + nI] = f2bf(v);
                    else if (part == 1)
                        C2[((size_t)((bI * Hh + hh) * Nv + nI)) * DHv + dd] = f2bf(v);
                    else
                        C3[((size_t)((bI * Hh + hh) * Nv + nI)) * DHv + dd] = f2bf(v);
                } else if (EPI == 1) {
                    ((float*)C0)[(size_t)m * N + col] = v + resid[(size_t)m * N + col];
                } else if (EPI == 2) {
                    v += bias[col];
                    ((short*)C0)[(size_t)m * N + col] = f2bf(v > 0.f ? v : 0.f);
                } else {
                    ((short*)C0)[(size_t)blockIdx.z * M * N + (size_t)m * N + col] = f2bf(v);
                }
            }
        }
    }
}

// ---------------------------------------------------------------------------
// out = P0 + P1 + bias + resid   (MLP2 split-K combine)
// ---------------------------------------------------------------------------
__global__ __launch_bounds__(256) void combine_mlp2(
    const short* __restrict__ P, const float* __restrict__ bias,
    const float* __restrict__ resid, float* __restrict__ out)
{
    int i = (blockIdx.x * 256 + threadIdx.x) * 4;
    float4 rz = *(const float4*)&resid[i];
    float4 bz = *(const float4*)&bias[i & 511];
    short4 p0 = *(const short4*)&P[i];
    short4 p1 = *(const short4*)&P[i + 2097152];
    float4 o;
    o.x = bf2f(p0.x) + bf2f(p1.x) + bz.x + rz.x;
    o.y = bf2f(p0.y) + bf2f(p1.y) + bz.y + rz.y;
    o.z = bf2f(p0.z) + bf2f(p1.z) + bz.z + rz.z;
    o.w = bf2f(p0.w) + bf2f(p1.w) + bz.w + rz.w;
    *(float4*)&out[i] = o;
}

// ---------------------------------------------------------------------------
// Flash attention: block = (b,h,64 q-rows), 4 waves x 16 rows, each wave
// owns ALL 1024 keys in 4 deinterleaved strips of 256 with in-register
// online merge. No cross-wave merge. XCD swizzle: blockIdx encodes
// (b,parity,qt,h) so each XCD (%8) sees one b, 8 q-tiles, all 8 heads ->
// its bias (2 MB) + K/V (2 MB) fit in the 4 MB per-XCD L2.
// ---------------------------------------------------------------------------
__global__ __launch_bounds__(256) void attn_mfma(
    const short* __restrict__ Q, const short* __restrict__ K,
    const short* __restrict__ Vt, const uint32_t* __restrict__ Bm,
    short* __restrict__ attn_l)
{
    __shared__ short Pl[4][16][264];

    int tid = threadIdx.x, lane = tid & 63, wave = tid >> 6;
    int n_lo = lane & 15, quad = lane >> 4;

    int idx = blockIdx.x;
    int b = idx & 3;
    int parity = (idx >> 2) & 1;
    int qt = ((idx >> 3) & 7) * 2 + parity;
    int h = idx >> 6;
    int q0 = qt * 64 + wave * 16;

    const short* Qp = Q + ((size_t)((b * Hh + h) * Nv + q0)) * DHv;
    const short* Kp = K + ((size_t)((b * Hh + h) * Nv)) * DHv;
    const short* Vp = Vt + ((size_t)((b * Hh + h) * DHv)) * Nv;
    const uint32_t* Bp = Bm + ((size_t)(b * Nv + q0)) * Nv;

    s16x8 a0 = *(const s16x8*)&Qp[n_lo * DHv + quad * 8];
    s16x8 a1 = *(const s16x8*)&Qp[n_lo * DHv + 32 + quad * 8];

    f32x4 O[4] = {};
    float m_run[4] = {-1e30f, -1e30f, -1e30f, -1e30f};
    float l_run[4] = {0.f, 0.f, 0.f, 0.f};
    short* Pw = &Pl[wave][0][0];

    for (int s = 0; s < 4; ++s) {
        int kbase = s * 256;
        const short* Ksp = Kp + (size_t)kbase * DHv;
        const uint32_t* Bsp = Bp + kbase;

        float sc[64];
        uint32_t mkp[32];

        // ---- phase A: 256 scores (independent loads/MFMA, pipelined) ----
#pragma unroll
        for (int it = 0; it < 8; ++it) {
            const short* kb = Ksp + (size_t)it * 32 * DHv;
            s16x8 k0a = *(const s16x8*)&kb[n_lo * DHv + quad * 8];
            s16x8 k0b = *(const s16x8*)&kb[n_lo * DHv + 32 + quad * 8];
            s16x8 k1a = *(const s16x8*)&kb[(16 + n_lo) * DHv + quad * 8];
            s16x8 k1b = *(const s16x8*)&kb[(16 + n_lo) * DHv + 32 + quad * 8];
            f32x4 z = {0.f, 0.f, 0.f, 0.f};
            f32x4 s0 = __builtin_amdgcn_mfma_f32_16x16x32_bf16(
                a1, k0b, __builtin_amdgcn_mfma_f32_16x16x32_bf16(a0, k0a, z, 0, 0, 0), 0, 0, 0);
            f32x4 s1 = __builtin_amdgcn_mfma_f32_16x16x32_bf16(
                a1, k1b, __builtin_amdgcn_mfma_f32_16x16x32_bf16(a0, k1a, z, 0, 0, 0), 0, 0, 0);
#pragma unroll
            for (int i = 0; i < 4; i++) {
                uint32_t u0 = Bsp[(size_t)(quad * 4 + i) * Nv + it * 32 + n_lo];
                uint32_t u1 = Bsp[(size_t)(quad * 4 + i) * Nv + it * 32 + 16 + n_lo];
                sc[it * 8 + i]     = s0[i] * 0.125f + __uint_as_float(u0 << 16);
                sc[it * 8 + 4 + i] = s1[i] * 0.125f + __uint_as_float(u1 << 16);
                mkp[it * 4 + i] = (u0 >> 16) | (u1 & 0xFFFF0000u);
            }
        }

        // ---- phase B: strip softmax stats ----
        float ms[4], ls[4];
#pragma unroll
        for (int i = 0; i < 4; i++) {
            float mx = sc[i];
#pragma unroll
            for (int it = 0; it < 8; it++) {
                mx = fmaxf(mx, sc[it * 8 + i]);
                mx = fmaxf(mx, sc[it * 8 + 4 + i]);
            }
#pragma unroll
            for (int off = 1; off < 16; off <<= 1) mx = fmaxf(mx, __shfl_xor(mx, off));
            ms[i] = mx;
            float su = 0.f;
#pragma unroll
            for (int it = 0; it < 8; it++) {
                float e0 = __expf(sc[it * 8 + i] - mx);
                float e1 = __expf(sc[it * 8 + 4 + i] - mx);
                sc[it * 8 + i] = e0;
                sc[it * 8 + 4 + i] = e1;
                su += e0 + e1;
            }
#pragma unroll
            for (int off = 1; off < 16; off <<= 1) su += __shfl_xor(su, off);
            ls[i] = su;
        }

        // ---- online merge into running state ----
        float beta[4];
#pragma unroll
        for (int i = 0; i < 4; i++) {
            float mn = fmaxf(m_run[i], ms[i]);
            float al = __expf(m_run[i] - mn);
            beta[i] = __expf(ms[i] - mn);
            l_run[i] = l_run[i] * al + ls[i] * beta[i];
            m_run[i] = mn;
#pragma unroll
            for (int t = 0; t < 4; t++) O[t][i] *= al;
        }

        // ---- phase C: P (masked, rescaled) -> LDS, then PV ----
#pragma unroll
        for (int it = 0; it < 8; it++)
#pragma unroll
            for (int i = 0; i < 4; i++) {
                int row = quad * 4 + i;
                float mk0 = __uint_as_float(mkp[it * 4 + i] << 16);
                float mk1 = __uint_as_float(mkp[it * 4 + i] & 0xFFFF0000u);
                Pw[row * 264 + it * 32 + n_lo]      = f2bf(sc[it * 8 + i] * mk0 * beta[i]);
                Pw[row * 264 + it * 32 + 16 + n_lo] = f2bf(sc[it * 8 + 4 + i] * mk1 * beta[i]);
            }

#pragma unroll
        for (int c = 0; c < 8; c++) {
            s16x8 pa = *(const s16x8*)&Pw[n_lo * 264 + c * 32 + quad * 8];
#pragma unroll
            for (int t = 0; t < 4; t++) {
                s16x8 vb = *(const s16x8*)&Vp[(size_t)(t * 16 + n_lo) * Nv + kbase + c * 32 + quad * 8];
                O[t] = __builtin_amdgcn_mfma_f32_16x16x32_bf16(pa, vb, O[t], 0, 0, 0);
            }
        }
    }

    // ---- epilogue: O/l, leaky relu, store ----
    float inv[4];
#pragma unroll
    for (int i = 0; i < 4; i++) inv[i] = 1.f / l_run[i];
#pragma unroll
    for (int t = 0; t < 4; t++)
#pragma unroll
        for (int i = 0; i < 4; i++) {
            float o = O[t][i] * inv[i];
            o = o > 0.f ? o : 0.01f * o;
            attn_l[((size_t)(b * Nv + q0 + quad * 4 + i)) * DM + h * DHv + t * 16 + n_lo] = f2bf(o);
        }
}

// ---------------------------------------------------------------------------
extern "C" void kernel_launch(void* const* d_in, const int* in_sizes, int n_in,
                              void* d_out, int out_size, void* d_ws, size_t ws_size,
                              hipStream_t stream)
{
    const float* Z     = (const float*)d_in[0];
    const float* D     = (const float*)d_in[1];
    const float* nmsk  = (const float*)d_in[2];
    const float* msk   = (const float*)d_in[3];
    const float* Wqkv  = (const float*)d_in[4];
    const float* bqkv  = (const float*)d_in[5];
    const float* Wo    = (const float*)d_in[6];
    const float* g1    = (const float*)d_in[7];
    const float* b1    = (const float*)d_in[8];
    const float* g2    = (const float*)d_in[9];
    const float* b2    = (const float*)d_in[10];
    const float* Wp1   = (const float*)d_in[11];
    const float* bp1   = (const float*)d_in[12];
    const float* Wp2   = (const float*)d_in[13];
    const float* bp2   = (const float*)d_in[14];
    const float* gamma = (const float*)d_in[15];
    float* out = (float*)d_out;
    char* w = (char*)d_ws;

    const size_t MB = 1048576;
    short*    WqkvB = (short*)(w);
    short*    WoB   = (short*)(w + 1572864);
    short*    Wp1B  = (short*)(w + 2 * MB);
    short*    Wp2B  = (short*)(w + 4 * MB);
    float*    Z2    = (float*)(w + 6 * MB);
    uint32_t* Bm    = (uint32_t*)(w + 14 * MB);
    short*    Zn    = (short*)(w + 30 * MB);
    short*    Qb    = (short*)(w + 34 * MB);
    short*    Kb    = (short*)(w + 38 * MB);
    short*    VtB   = (short*)(w + 42 * MB);
    short*    AtnL  = (short*)(w + 30 * MB);
    short*    Zn2   = (short*)(w + 14 * MB);
    short*    Hb    = (short*)(w + 18 * MB);
    short*    Pp    = (short*)(w + 34 * MB);

    conv_all<<<3072, 256, 0, stream>>>(Wqkv, Wo, Wp1, Wp2, WqkvB, WoB, Wp1B, Wp2B);
    prep_bm<<<4096, 256, 0, stream>>>(D, nmsk, msk, gamma, Bm);
    ln_kernel<<<TOKc, 256, 0, stream>>>(Z, g1, b1, Zn);
    gemm_bf16<0, 128, 64><<<dim3(24, 32), 256, 0, stream>>>(
        Zn, WqkvB, bqkv, nullptr, VtB, Qb, Kb, TOKc, 1536, 512, 512);
    attn_mfma<<<dim3(512), 256, 0, stream>>>(Qb, Kb, VtB, Bm, AtnL);
    gemm_bf16<1, 64, 64><<<dim3(8, 64), 256, 0, stream>>>(
        AtnL, WoB, nullptr, Z, Z2, nullptr, nullptr, TOKc, 512, 512, 512);
    ln_kernel<<<TOKc, 256, 0, stream>>>(Z2, g2, b2, Zn2);
    gemm_bf16<2, 128, 64><<<dim3(32, 32), 256, 0, stream>>>(
        Zn2, Wp1B, bp1, nullptr, Hb, nullptr, nullptr, TOKc, 2048, 512, 512);
    gemm_bf16<4, 128, 64><<<dim3(8, 32, 2), 256, 0, stream>>>(
        Hb, Wp2B, nullptr, nullptr, Pp, nullptr, nullptr, TOKc, 512, 1024, 2048);
    combine_mlp2<<<2048, 256, 0, stream>>>(Pp, bp2, Z2, out);
}

// Round 6
// 275.496 us; speedup vs baseline: 1.0744x; 1.0744x over previous
//
#include <hip/hip_runtime.h>
#include <hip/hip_bf16.h>
#include <cstddef>
#include <cstdint>

#define Bv 4
#define Nv 1024
#define DM 512
#define Hh 8
#define DHv 64
#define TOKc 4096

typedef __attribute__((ext_vector_type(4))) float f32x4;
typedef __attribute__((ext_vector_type(8))) short s16x8;

__device__ __forceinline__ uint32_t f2bf_bits(float f) {
    uint32_t x = __float_as_uint(f);
    return (x + 0x7FFFu + ((x >> 16) & 1u)) >> 16;
}
__device__ __forceinline__ short f2bf(float f) { return (short)f2bf_bits(f); }
__device__ __forceinline__ float bf2f(short s) {
    return __uint_as_float(((uint32_t)(uint16_t)s) << 16);
}

__device__ __forceinline__ void g2lds16(const void* g, void* l) {
    __builtin_amdgcn_global_load_lds(
        (const __attribute__((address_space(1))) void*)g,
        (__attribute__((address_space(3))) void*)l, 16, 0, 0);
}

// ---------------------------------------------------------------------------
// all 4 weight tensors -> bf16, one launch
// ---------------------------------------------------------------------------
__global__ __launch_bounds__(256) void conv_all(
    const float* __restrict__ W0, const float* __restrict__ W1,
    const float* __restrict__ W2, const float* __restrict__ W3,
    short* __restrict__ D0, short* __restrict__ D1,
    short* __restrict__ D2, short* __restrict__ D3)
{
    int bid = blockIdx.x;
    const float* s; short* d; int base;
    if (bid < 768)       { s = W0; d = D0; base = bid * 1024; }
    else if (bid < 1024) { s = W1; d = D1; base = (bid - 768) * 1024; }
    else if (bid < 2048) { s = W2; d = D2; base = (bid - 1024) * 1024; }
    else                 { s = W3; d = D3; base = (bid - 2048) * 1024; }
    int i = base + threadIdx.x * 4;
    float4 v = *(const float4*)&s[i];
    short4 o = { f2bf(v.x), f2bf(v.y), f2bf(v.z), f2bf(v.w) };
    *(short4*)&d[i] = o;
}

// ---------------------------------------------------------------------------
// pack bias = new_mask - gamma*D (lo bf16) and mask (hi bf16) into u32,
// PERMUTED within each row so attention lanes can load pairs with b64:
// per row of 1024 keys: 32 tiles of 32 keys; within tile: pos = j*2+half
// holds key = tile*32 + half*16 + j  (j = lane n_lo 0..15)
// ---------------------------------------------------------------------------
__global__ __launch_bounds__(256) void prep_bm2(
    const float* __restrict__ Dm, const float* __restrict__ nm,
    const float* __restrict__ mk, const float* __restrict__ gamma,
    uint32_t* __restrict__ out)
{
    int o = (blockIdx.x * 256 + threadIdx.x) * 4;   // 4 consecutive u32 outputs
    float g = gamma[0];
    size_t row = o >> 10;                // b*1024 + n
    int p = o & 1023;
    int t = p >> 5;
    const float* Dr = Dm + row * 1024 + t * 32;
    const float* Nr = nm + row * 1024 + t * 32;
    const float* Mr = mk + row * 1024 + t * 32;
    uint4 ov;
    uint32_t* po = &ov.x;
#pragma unroll
    for (int q = 0; q < 4; q++) {
        int pp = (p & 31) + q;
        int j = (pp >> 1) & 15, half = pp & 1;
        int key = half * 16 + j;
        float bias = Nr[key] - g * Dr[key];
        po[q] = f2bf_bits(bias) | (f2bf_bits(Mr[key]) << 16);
    }
    *(uint4*)&out[o] = ov;
}

// ---------------------------------------------------------------------------
// LayerNorm -> bf16 out
// ---------------------------------------------------------------------------
__global__ __launch_bounds__(256) void ln_kernel(
    const float* __restrict__ X, const float* __restrict__ g,
    const float* __restrict__ bb, short* __restrict__ Y)
{
    __shared__ float red[8];
    int row = blockIdx.x, tid = threadIdx.x;
    const float* x = X + (size_t)row * DM;
    float v0 = x[tid], v1 = x[tid + 256];
    float s = v0 + v1, ss = v0 * v0 + v1 * v1;
#pragma unroll
    for (int o = 32; o > 0; o >>= 1) {
        s += __shfl_xor(s, o);
        ss += __shfl_xor(ss, o);
    }
    int lane = tid & 63, wid = tid >> 6;
    if (lane == 0) { red[wid] = s; red[4 + wid] = ss; }
    __syncthreads();
    float S = red[0] + red[1] + red[2] + red[3];
    float SS = red[4] + red[5] + red[6] + red[7];
    float mean = S * (1.f / DM);
    float var = SS * (1.f / DM) - mean * mean;
    float rstd = rsqrtf(var + 1e-5f);
    short* y = Y + (size_t)row * DM;
    y[tid]       = f2bf((v0 - mean) * rstd * g[tid]       + bb[tid]);
    y[tid + 256] = f2bf((v1 - mean) * rstd * g[tid + 256] + bb[tid + 256]);
}

// ---------------------------------------------------------------------------
// bf16 MFMA NT GEMM, BK=64 (unchanged from R5)
// ---------------------------------------------------------------------------
template <int EPI, int BM, int BN>
__global__ __launch_bounds__(256) void gemm_bf16(
    const short* __restrict__ A, const short* __restrict__ Bw,
    const float* __restrict__ bias, const float* __restrict__ resid,
    void* __restrict__ C0, short* __restrict__ C2, short* __restrict__ C3,
    int M, int N, int Ks, int Kst)
{
    constexpr int FI = BM / 32, FJ = BN / 32;
    __shared__ short As0[BM * 32];
    __shared__ short As1[BM * 32];
    __shared__ short Bs0[BN * 32];
    __shared__ short Bs1[BN * 32];
    int tid = threadIdx.x;
    int lane = tid & 63, wave = tid >> 6;
    int bm = blockIdx.y * BM, bn = blockIdx.x * BN;
    int wm = (wave >> 1) * (BM / 2), wn = (wave & 1) * (BN / 2);
    int n_lo = lane & 15, quad = lane >> 4;

    f32x4 acc[FI][FJ] = {};

    int koff = (EPI == 4) ? blockIdx.z * Ks : 0;
    int lrow = lane >> 2, lchunk = (lane & 3) * 8;
    const short* Ag = A + (size_t)(bm + wave * (BM / 4) + lrow) * Kst + koff + lchunk;
    const short* Bg = Bw + (size_t)(bn + wave * (BN / 4) + lrow) * Kst + koff + lchunk;

    for (int k0 = 0; k0 < Ks; k0 += 64) {
        __syncthreads();
#pragma unroll
        for (int r = 0; r < BM / 64; r++) {
            g2lds16(Ag + (size_t)r * 16 * Kst + k0,      &As0[(wave * (BM / 4) + r * 16) * 32]);
            g2lds16(Ag + (size_t)r * 16 * Kst + k0 + 32, &As1[(wave * (BM / 4) + r * 16) * 32]);
        }
#pragma unroll
        for (int r = 0; r < BN / 64; r++) {
            g2lds16(Bg + (size_t)r * 16 * Kst + k0,      &Bs0[(wave * (BN / 4) + r * 16) * 32]);
            g2lds16(Bg + (size_t)r * 16 * Kst + k0 + 32, &Bs1[(wave * (BN / 4) + r * 16) * 32]);
        }
        __syncthreads();
        s16x8 af0[FI], af1[FI], bf0[FJ], bf1[FJ];
#pragma unroll
        for (int i = 0; i < FI; i++) {
            af0[i] = *(const s16x8*)&As0[(wm + i * 16 + n_lo) * 32 + quad * 8];
            af1[i] = *(const s16x8*)&As1[(wm + i * 16 + n_lo) * 32 + quad * 8];
        }
#pragma unroll
        for (int j = 0; j < FJ; j++) {
            bf0[j] = *(const s16x8*)&Bs0[(wn + j * 16 + n_lo) * 32 + quad * 8];
            bf1[j] = *(const s16x8*)&Bs1[(wn + j * 16 + n_lo) * 32 + quad * 8];
        }
#pragma unroll
        for (int i = 0; i < FI; i++)
#pragma unroll
            for (int j = 0; j < FJ; j++)
                acc[i][j] = __builtin_amdgcn_mfma_f32_16x16x32_bf16(
                    af0[i], bf0[j], acc[i][j], 0, 0, 0);
#pragma unroll
        for (int i = 0; i < FI; i++)
#pragma unroll
            for (int j = 0; j < FJ; j++)
                acc[i][j] = __builtin_amdgcn_mfma_f32_16x16x32_bf16(
                    af1[i], bf1[j], acc[i][j], 0, 0, 0);
    }

#pragma unroll
    for (int i = 0; i < FI; i++) {
#pragma unroll
        for (int j = 0; j < FJ; j++) {
            int col = bn + wn + j * 16 + n_lo;
#pragma unroll
            for (int r = 0; r < 4; r++) {
                int m = bm + wm + i * 16 + quad * 4 + r;
                float v = acc[i][j][r];
                if (EPI == 0) {
                    v += bias[col];
                    int hh = col / 192;
                    int rr = col - hh * 192;
                    int part = rr >> 6, dd = rr & 63;
                    int bI = m >> 10, nI = m & 1023;
                    if (part == 0)
                        ((short*)C0)[((size_t)((bI * Hh + hh) * DHv + dd)) * Nv + nI] = f2bf(v);
                    else if (part == 1)
                        C2[((size_t)((bI * Hh + hh) * Nv + nI)) * DHv + dd] = f2bf(v);
                    else
                        C3[((size_t)((bI * Hh + hh) * Nv + nI)) * DHv + dd] = f2bf(v);
                } else if (EPI == 1) {
                    ((float*)C0)[(size_t)m * N + col] = v + resid[(size_t)m * N + col];
                } else if (EPI == 2) {
                    v += bias[col];
                    ((short*)C0)[(size_t)m * N + col] = f2bf(v > 0.f ? v : 0.f);
                } else {
                    ((short*)C0)[(size_t)blockIdx.z * M * N + (size_t)m * N + col] = f2bf(v);
                }
            }
        }
    }
}

// ---------------------------------------------------------------------------
// out = P0 + P1 + bias + resid   (MLP2 split-K combine)
// ---------------------------------------------------------------------------
__global__ __launch_bounds__(256) void combine_mlp2(
    const short* __restrict__ P, const float* __restrict__ bias,
    const float* __restrict__ resid, float* __restrict__ out)
{
    int i = (blockIdx.x * 256 + threadIdx.x) * 4;
    float4 rz = *(const float4*)&resid[i];
    float4 bz = *(const float4*)&bias[i & 511];
    short4 p0 = *(const short4*)&P[i];
    short4 p1 = *(const short4*)&P[i + 2097152];
    float4 o;
    o.x = bf2f(p0.x) + bf2f(p1.x) + bz.x + rz.x;
    o.y = bf2f(p0.y) + bf2f(p1.y) + bz.y + rz.y;
    o.z = bf2f(p0.z) + bf2f(p1.z) + bz.z + rz.z;
    o.w = bf2f(p0.w) + bf2f(p1.w) + bz.w + rz.w;
    *(float4*)&out[i] = o;
}

// ---------------------------------------------------------------------------
// Flash attention, FIXED-MAX softmax (scores bounded; clamp@60 guard):
// block = (b,h,16 q-rows), 4 waves = 4 key-strips of 256; exp applied
// inline (no cross-lane reduction in hot loop); l summed in-lane, one
// shuffle-reduce + plain-sum cross-wave merge at the end.
// Grid 2048 1D, XCD-swizzled: bid&7 -> XCD; each XCD sees 4 (b,h) pairs
// so its K/V working set (1 MB) locks into the 4 MB per-XCD L2.
// ---------------------------------------------------------------------------
__global__ __launch_bounds__(256) void attn_mfma(
    const short* __restrict__ Q, const short* __restrict__ K,
    const short* __restrict__ Vt, const uint32_t* __restrict__ Bm,
    short* __restrict__ attn_l)
{
    __shared__ __align__(16) char smem[4 * 16 * 264 * 2];  // 33792 B union
    int tid = threadIdx.x, lane = tid & 63, wave = tid >> 6;
    int n_lo = lane & 15, quad = lane >> 4;

    int bid = blockIdx.x;
    int bh = (bid & 7) * 4 + ((bid >> 3) & 3);   // 0..31, XCD-local group of 4
    int qt = bid >> 5;                            // 0..63
    int b = bh >> 3, h = bh & 7;
    int q0 = qt * 16;
    int kbase = wave * 256;

    const short* Qp = Q + ((size_t)((b * Hh + h) * Nv + q0)) * DHv;
    const short* Kp = K + ((size_t)((b * Hh + h) * Nv + kbase)) * DHv;
    const short* Vp = Vt + ((size_t)((b * Hh + h) * DHv)) * Nv;
    // permuted bias: row-major, per row 32 tiles x (n_lo*2+half)
    const uint32_t* Bp = Bm + ((size_t)(b * Nv + q0)) * Nv + (kbase >> 5) * 32;

    s16x8 a0 = *(const s16x8*)&Qp[n_lo * DHv + quad * 8];
    s16x8 a1 = *(const s16x8*)&Qp[n_lo * DHv + 32 + quad * 8];

    short* Pw = (short*)smem + wave * (16 * 264);
    f32x4 O[4] = {};
    float lacc[4] = {0.f, 0.f, 0.f, 0.f};

#pragma unroll
    for (int it = 0; it < 8; ++it) {
        const short* kb = Kp + (size_t)it * 32 * DHv;
        s16x8 k0a = *(const s16x8*)&kb[n_lo * DHv + quad * 8];
        s16x8 k0b = *(const s16x8*)&kb[n_lo * DHv + 32 + quad * 8];
        s16x8 k1a = *(const s16x8*)&kb[(16 + n_lo) * DHv + quad * 8];
        s16x8 k1b = *(const s16x8*)&kb[(16 + n_lo) * DHv + 32 + quad * 8];
        f32x4 z = {0.f, 0.f, 0.f, 0.f};
        f32x4 s0 = __builtin_amdgcn_mfma_f32_16x16x32_bf16(
            a1, k0b, __builtin_amdgcn_mfma_f32_16x16x32_bf16(a0, k0a, z, 0, 0, 0), 0, 0, 0);
        f32x4 s1 = __builtin_amdgcn_mfma_f32_16x16x32_bf16(
            a1, k1b, __builtin_amdgcn_mfma_f32_16x16x32_bf16(a0, k1a, z, 0, 0, 0), 0, 0, 0);
#pragma unroll
        for (int i = 0; i < 4; i++) {
            int row = quad * 4 + i;
            uint2 u = *(const uint2*)&Bp[(size_t)row * Nv + it * 32 + n_lo * 2];
            float e0 = __expf(fminf(s0[i] * 0.125f + __uint_as_float(u.x << 16), 60.f));
            float e1 = __expf(fminf(s1[i] * 0.125f + __uint_as_float(u.y << 16), 60.f));
            lacc[i] += e0 + e1;
            Pw[row * 264 + it * 32 + n_lo]      = f2bf(e0 * __uint_as_float(u.x & 0xFFFF0000u));
            Pw[row * 264 + it * 32 + 16 + n_lo] = f2bf(e1 * __uint_as_float(u.y & 0xFFFF0000u));
        }
    }

#pragma unroll
    for (int c = 0; c < 8; c++) {
        s16x8 pa = *(const s16x8*)&Pw[n_lo * 264 + c * 32 + quad * 8];
#pragma unroll
        for (int t = 0; t < 4; t++) {
            s16x8 vb = *(const s16x8*)&Vp[(size_t)(t * 16 + n_lo) * Nv + kbase + c * 32 + quad * 8];
            O[t] = __builtin_amdgcn_mfma_f32_16x16x32_bf16(pa, vb, O[t], 0, 0, 0);
        }
    }

    // in-lane l -> row l (sum over 16 lanes)
#pragma unroll
    for (int i = 0; i < 4; i++)
#pragma unroll
        for (int off = 1; off < 16; off <<= 1) lacc[i] += __shfl_xor(lacc[i], off);

    // cross-wave plain-sum merge (union LDS: Osh/Lsh overlay Pw after barrier)
    __syncthreads();
    float (*Osh)[16][68] = (float(*)[16][68])smem;
    float* Lsh = (float*)(smem + 4 * 16 * 68 * 4);   // [4][16] at 17408
#pragma unroll
    for (int t = 0; t < 4; t++)
#pragma unroll
        for (int i = 0; i < 4; i++)
            Osh[wave][quad * 4 + i][t * 16 + n_lo] = O[t][i];
    if (n_lo == 0) {
#pragma unroll
        for (int i = 0; i < 4; i++) Lsh[wave * 16 + quad * 4 + i] = lacc[i];
    }
    __syncthreads();

    int col = tid & 63, rb = (tid >> 6) * 4;
#pragma unroll
    for (int r = 0; r < 4; r++) {
        int row = rb + r;
        float s = Osh[0][row][col] + Osh[1][row][col] + Osh[2][row][col] + Osh[3][row][col];
        float lt = Lsh[row] + Lsh[16 + row] + Lsh[32 + row] + Lsh[48 + row];
        float o = s / lt;
        o = o > 0.f ? o : 0.01f * o;
        attn_l[((size_t)(b * Nv + q0 + row)) * DM + h * DHv + col] = f2bf(o);
    }
}

// ---------------------------------------------------------------------------
extern "C" void kernel_launch(void* const* d_in, const int* in_sizes, int n_in,
                              void* d_out, int out_size, void* d_ws, size_t ws_size,
                              hipStream_t stream)
{
    const float* Z     = (const float*)d_in[0];
    const float* D     = (const float*)d_in[1];
    const float* nmsk  = (const float*)d_in[2];
    const float* msk   = (const float*)d_in[3];
    const float* Wqkv  = (const float*)d_in[4];
    const float* bqkv  = (const float*)d_in[5];
    const float* Wo    = (const float*)d_in[6];
    const float* g1    = (const float*)d_in[7];
    const float* b1    = (const float*)d_in[8];
    const float* g2    = (const float*)d_in[9];
    const float* b2    = (const float*)d_in[10];
    const float* Wp1   = (const float*)d_in[11];
    const float* bp1   = (const float*)d_in[12];
    const float* Wp2   = (const float*)d_in[13];
    const float* bp2   = (const float*)d_in[14];
    const float* gamma = (const float*)d_in[15];
    float* out = (float*)d_out;
    char* w = (char*)d_ws;

    const size_t MB = 1048576;
    short*    WqkvB = (short*)(w);
    short*    WoB   = (short*)(w + 1572864);
    short*    Wp1B  = (short*)(w + 2 * MB);
    short*    Wp2B  = (short*)(w + 4 * MB);
    float*    Z2    = (float*)(w + 6 * MB);
    uint32_t* Bm    = (uint32_t*)(w + 14 * MB);
    short*    Zn    = (short*)(w + 30 * MB);
    short*    Qb    = (short*)(w + 34 * MB);
    short*    Kb    = (short*)(w + 38 * MB);
    short*    VtB   = (short*)(w + 42 * MB);
    short*    AtnL  = (short*)(w + 30 * MB);
    short*    Zn2   = (short*)(w + 14 * MB);
    short*    Hb    = (short*)(w + 18 * MB);
    short*    Pp    = (short*)(w + 34 * MB);

    conv_all<<<3072, 256, 0, stream>>>(Wqkv, Wo, Wp1, Wp2, WqkvB, WoB, Wp1B, Wp2B);
    prep_bm2<<<4096, 256, 0, stream>>>(D, nmsk, msk, gamma, Bm);
    ln_kernel<<<TOKc, 256, 0, stream>>>(Z, g1, b1, Zn);
    gemm_bf16<0, 128, 64><<<dim3(24, 32), 256, 0, stream>>>(
        Zn, WqkvB, bqkv, nullptr, VtB, Qb, Kb, TOKc, 1536, 512, 512);
    attn_mfma<<<dim3(2048), 256, 0, stream>>>(Qb, Kb, VtB, Bm, AtnL);
    gemm_bf16<1, 64, 64><<<dim3(8, 64), 256, 0, stream>>>(
        AtnL, WoB, nullptr, Z, Z2, nullptr, nullptr, TOKc, 512, 512, 512);
    ln_kernel<<<TOKc, 256, 0, stream>>>(Z2, g2, b2, Zn2);
    gemm_bf16<2, 128, 64><<<dim3(32, 32), 256, 0, stream>>>(
        Zn2, Wp1B, bp1, nullptr, Hb, nullptr, nullptr, TOKc, 2048, 512, 512);
    gemm_bf16<4, 128, 64><<<dim3(8, 32, 2), 256, 0, stream>>>(
        Hb, Wp2B, nullptr, nullptr, Pp, nullptr, nullptr, TOKc, 512, 1024, 2048);
    combine_mlp2<<<2048, 256, 0, stream>>>(Pp, bp2, Z2, out);
}

// Round 7
// 235.194 us; speedup vs baseline: 1.2585x; 1.1714x over previous
//
#include <hip/hip_runtime.h>
#include <hip/hip_bf16.h>
#include <cstddef>
#include <cstdint>

#define Bv 4
#define Nv 1024
#define DM 512
#define Hh 8
#define DHv 64
#define TOKc 4096

typedef __attribute__((ext_vector_type(4))) float f32x4;
typedef __attribute__((ext_vector_type(8))) short s16x8;

__device__ __forceinline__ uint32_t f2bf_bits(float f) {
    uint32_t x = __float_as_uint(f);
    return (x + 0x7FFFu + ((x >> 16) & 1u)) >> 16;
}
__device__ __forceinline__ short f2bf(float f) { return (short)f2bf_bits(f); }
__device__ __forceinline__ float bf2f(short s) {
    return __uint_as_float(((uint32_t)(uint16_t)s) << 16);
}

__device__ __forceinline__ void g2lds16(const void* g, void* l) {
    __builtin_amdgcn_global_load_lds(
        (const __attribute__((address_space(1))) void*)g,
        (__attribute__((address_space(3))) void*)l, 16, 0, 0);
}

// ---------------------------------------------------------------------------
// all 4 weight tensors -> bf16, one launch
// ---------------------------------------------------------------------------
__global__ __launch_bounds__(256) void conv_all(
    const float* __restrict__ W0, const float* __restrict__ W1,
    const float* __restrict__ W2, const float* __restrict__ W3,
    short* __restrict__ D0, short* __restrict__ D1,
    short* __restrict__ D2, short* __restrict__ D3)
{
    int bid = blockIdx.x;
    const float* s; short* d; int base;
    if (bid < 768)       { s = W0; d = D0; base = bid * 1024; }
    else if (bid < 1024) { s = W1; d = D1; base = (bid - 768) * 1024; }
    else if (bid < 2048) { s = W2; d = D2; base = (bid - 1024) * 1024; }
    else                 { s = W3; d = D3; base = (bid - 2048) * 1024; }
    int i = base + threadIdx.x * 4;
    float4 v = *(const float4*)&s[i];
    short4 o = { f2bf(v.x), f2bf(v.y), f2bf(v.z), f2bf(v.w) };
    *(short4*)&d[i] = o;
}

// ---------------------------------------------------------------------------
// pack bias = new_mask - gamma*D (lo bf16) and mask (hi bf16) into u32,
// PERMUTED within each 32-key group: pos j*2+half holds key half*16+j
// (j = lane n_lo) so a lane's two keys (n_lo, 16+n_lo) are adjacent u32s.
// ---------------------------------------------------------------------------
__global__ __launch_bounds__(256) void prep_bm2(
    const float* __restrict__ Dm, const float* __restrict__ nm,
    const float* __restrict__ mk, const float* __restrict__ gamma,
    uint32_t* __restrict__ out)
{
    int o = (blockIdx.x * 256 + threadIdx.x) * 4;
    float g = gamma[0];
    size_t row = o >> 10;
    int p = o & 1023;
    int t = p >> 5;
    const float* Dr = Dm + row * 1024 + t * 32;
    const float* Nr = nm + row * 1024 + t * 32;
    const float* Mr = mk + row * 1024 + t * 32;
    uint4 ov;
    uint32_t* po = &ov.x;
#pragma unroll
    for (int q = 0; q < 4; q++) {
        int pp = (p & 31) + q;
        int j = (pp >> 1) & 15, half = pp & 1;
        int key = half * 16 + j;
        float bias = Nr[key] - g * Dr[key];
        po[q] = f2bf_bits(bias) | (f2bf_bits(Mr[key]) << 16);
    }
    *(uint4*)&out[o] = ov;
}

// ---------------------------------------------------------------------------
// LayerNorm -> bf16 out
// ---------------------------------------------------------------------------
__global__ __launch_bounds__(256) void ln_kernel(
    const float* __restrict__ X, const float* __restrict__ g,
    const float* __restrict__ bb, short* __restrict__ Y)
{
    __shared__ float red[8];
    int row = blockIdx.x, tid = threadIdx.x;
    const float* x = X + (size_t)row * DM;
    float v0 = x[tid], v1 = x[tid + 256];
    float s = v0 + v1, ss = v0 * v0 + v1 * v1;
#pragma unroll
    for (int o = 32; o > 0; o >>= 1) {
        s += __shfl_xor(s, o);
        ss += __shfl_xor(ss, o);
    }
    int lane = tid & 63, wid = tid >> 6;
    if (lane == 0) { red[wid] = s; red[4 + wid] = ss; }
    __syncthreads();
    float S = red[0] + red[1] + red[2] + red[3];
    float SS = red[4] + red[5] + red[6] + red[7];
    float mean = S * (1.f / DM);
    float var = SS * (1.f / DM) - mean * mean;
    float rstd = rsqrtf(var + 1e-5f);
    short* y = Y + (size_t)row * DM;
    y[tid]       = f2bf((v0 - mean) * rstd * g[tid]       + bb[tid]);
    y[tid + 256] = f2bf((v1 - mean) * rstd * g[tid + 256] + bb[tid + 256]);
}

// ---------------------------------------------------------------------------
// bf16 MFMA NT GEMM, BK=64 (unchanged from R6)
// ---------------------------------------------------------------------------
template <int EPI, int BM, int BN>
__global__ __launch_bounds__(256) void gemm_bf16(
    const short* __restrict__ A, const short* __restrict__ Bw,
    const float* __restrict__ bias, const float* __restrict__ resid,
    void* __restrict__ C0, short* __restrict__ C2, short* __restrict__ C3,
    int M, int N, int Ks, int Kst)
{
    constexpr int FI = BM / 32, FJ = BN / 32;
    __shared__ short As0[BM * 32];
    __shared__ short As1[BM * 32];
    __shared__ short Bs0[BN * 32];
    __shared__ short Bs1[BN * 32];
    int tid = threadIdx.x;
    int lane = tid & 63, wave = tid >> 6;
    int bm = blockIdx.y * BM, bn = blockIdx.x * BN;
    int wm = (wave >> 1) * (BM / 2), wn = (wave & 1) * (BN / 2);
    int n_lo = lane & 15, quad = lane >> 4;

    f32x4 acc[FI][FJ] = {};

    int koff = (EPI == 4) ? blockIdx.z * Ks : 0;
    int lrow = lane >> 2, lchunk = (lane & 3) * 8;
    const short* Ag = A + (size_t)(bm + wave * (BM / 4) + lrow) * Kst + koff + lchunk;
    const short* Bg = Bw + (size_t)(bn + wave * (BN / 4) + lrow) * Kst + koff + lchunk;

    for (int k0 = 0; k0 < Ks; k0 += 64) {
        __syncthreads();
#pragma unroll
        for (int r = 0; r < BM / 64; r++) {
            g2lds16(Ag + (size_t)r * 16 * Kst + k0,      &As0[(wave * (BM / 4) + r * 16) * 32]);
            g2lds16(Ag + (size_t)r * 16 * Kst + k0 + 32, &As1[(wave * (BM / 4) + r * 16) * 32]);
        }
#pragma unroll
        for (int r = 0; r < BN / 64; r++) {
            g2lds16(Bg + (size_t)r * 16 * Kst + k0,      &Bs0[(wave * (BN / 4) + r * 16) * 32]);
            g2lds16(Bg + (size_t)r * 16 * Kst + k0 + 32, &Bs1[(wave * (BN / 4) + r * 16) * 32]);
        }
        __syncthreads();
        s16x8 af0[FI], af1[FI], bf0[FJ], bf1[FJ];
#pragma unroll
        for (int i = 0; i < FI; i++) {
            af0[i] = *(const s16x8*)&As0[(wm + i * 16 + n_lo) * 32 + quad * 8];
            af1[i] = *(const s16x8*)&As1[(wm + i * 16 + n_lo) * 32 + quad * 8];
        }
#pragma unroll
        for (int j = 0; j < FJ; j++) {
            bf0[j] = *(const s16x8*)&Bs0[(wn + j * 16 + n_lo) * 32 + quad * 8];
            bf1[j] = *(const s16x8*)&Bs1[(wn + j * 16 + n_lo) * 32 + quad * 8];
        }
#pragma unroll
        for (int i = 0; i < FI; i++)
#pragma unroll
            for (int j = 0; j < FJ; j++)
                acc[i][j] = __builtin_amdgcn_mfma_f32_16x16x32_bf16(
                    af0[i], bf0[j], acc[i][j], 0, 0, 0);
#pragma unroll
        for (int i = 0; i < FI; i++)
#pragma unroll
            for (int j = 0; j < FJ; j++)
                acc[i][j] = __builtin_amdgcn_mfma_f32_16x16x32_bf16(
                    af1[i], bf1[j], acc[i][j], 0, 0, 0);
    }

#pragma unroll
    for (int i = 0; i < FI; i++) {
#pragma unroll
        for (int j = 0; j < FJ; j++) {
            int col = bn + wn + j * 16 + n_lo;
#pragma unroll
            for (int r = 0; r < 4; r++) {
                int m = bm + wm + i * 16 + quad * 4 + r;
                float v = acc[i][j][r];
                if (EPI == 0) {
                    v += bias[col];
                    int hh = col / 192;
                    int rr = col - hh * 192;
                    int part = rr >> 6, dd = rr & 63;
                    int bI = m >> 10, nI = m & 1023;
                    if (part == 0)
                        ((short*)C0)[((size_t)((bI * Hh + hh) * DHv + dd)) * Nv + nI] = f2bf(v);
                    else if (part == 1)
                        C2[((size_t)((bI * Hh + hh) * Nv + nI)) * DHv + dd] = f2bf(v);
                    else
                        C3[((size_t)((bI * Hh + hh) * Nv + nI)) * DHv + dd] = f2bf(v);
                } else if (EPI == 1) {
                    ((float*)C0)[(size_t)m * N + col] = v + resid[(size_t)m * N + col];
                } else if (EPI == 2) {
                    v += bias[col];
                    ((short*)C0)[(size_t)m * N + col] = f2bf(v > 0.f ? v : 0.f);
                } else {
                    ((short*)C0)[(size_t)blockIdx.z * M * N + (size_t)m * N + col] = f2bf(v);
                }
            }
        }
    }
}

// ---------------------------------------------------------------------------
// out = P0 + P1 + bias + resid   (MLP2 split-K combine)
// ---------------------------------------------------------------------------
__global__ __launch_bounds__(256) void combine_mlp2(
    const short* __restrict__ P, const float* __restrict__ bias,
    const float* __restrict__ resid, float* __restrict__ out)
{
    int i = (blockIdx.x * 256 + threadIdx.x) * 4;
    float4 rz = *(const float4*)&resid[i];
    float4 bz = *(const float4*)&bias[i & 511];
    short4 p0 = *(const short4*)&P[i];
    short4 p1 = *(const short4*)&P[i + 2097152];
    float4 o;
    o.x = bf2f(p0.x) + bf2f(p1.x) + bz.x + rz.x;
    o.y = bf2f(p0.y) + bf2f(p1.y) + bz.y + rz.y;
    o.z = bf2f(p0.z) + bf2f(p1.z) + bz.z + rz.z;
    o.w = bf2f(p0.w) + bf2f(p1.w) + bz.w + rz.w;
    *(float4*)&out[i] = o;
}

// ---------------------------------------------------------------------------
// Flash attention, LDS-STAGED (m97 discipline): block = (b,h,64 q-rows),
// 4 waves x 16 rows. Loop over 16 key-tiles of 64; per tile K (8 KB),
// V^T (8 KB) and packed bias (16 KB) are cooperatively staged via
// global_load_lds (async, 8 instr/wave), then consumed from LDS.
// Hot loop has ZERO blocking global loads. Fixed-max softmax (clamp 60);
// each wave owns its rows across all keys -> no cross-wave merge.
// ---------------------------------------------------------------------------
__global__ __launch_bounds__(256) void attn_mfma(
    const short* __restrict__ Q, const short* __restrict__ K,
    const short* __restrict__ Vt, const uint32_t* __restrict__ Bm,
    short* __restrict__ attn_l)
{
    __shared__ short Ksh[64 * 64];        // [key][d]   8 KB
    __shared__ short Vsh[64 * 64];        // [d][key]   8 KB
    __shared__ uint32_t Bsh[64 * 64];     // [q][slot] 16 KB (permuted slots)
    __shared__ short Ph[4][16 * 72];      // wave-private P, 9 KB

    int tid = threadIdx.x, lane = tid & 63, wave = tid >> 6;
    int n_lo = lane & 15, quad = lane >> 4;

    int bid = blockIdx.x;
    int x = bid & 7, inner = bid >> 3;    // XCD swizzle: 64 blocks per XCD
    int bh = x * 4 + (inner & 3);         // 4 (b,h) pairs per XCD
    int qt = inner >> 2;                  // 0..15
    int b = bh >> 3, h = bh & 7;
    int q0 = qt * 64;
    int qw = q0 + wave * 16;

    const short* Qp = Q + ((size_t)((b * Hh + h) * Nv + qw)) * DHv;
    const short* Kp = K + ((size_t)((b * Hh + h) * Nv)) * DHv;
    const short* Vp = Vt + ((size_t)((b * Hh + h) * DHv)) * Nv;
    const uint32_t* Bp = Bm + ((size_t)(b * Nv + q0)) * Nv;

    s16x8 a0 = *(const s16x8*)&Qp[n_lo * DHv + quad * 8];
    s16x8 a1 = *(const s16x8*)&Qp[n_lo * DHv + 32 + quad * 8];

    f32x4 O[4] = {};
    float lacc[4] = {0.f, 0.f, 0.f, 0.f};
    short* Pw = Ph[wave];

    for (int kt = 0; kt < 16; ++kt) {
        int key0 = kt * 64;
        __syncthreads();
        // K: 8 instrs (2/wave), each 8 key-rows of 128 B
        // V: 8 instrs (2/wave), each 8 d-rows of 128 B
#pragma unroll
        for (int s = 0; s < 2; s++) {
            int si = wave * 2 + s;
            g2lds16(Kp + (size_t)(key0 + si * 8 + (lane >> 3)) * DHv + (lane & 7) * 8,
                    &Ksh[si * 8 * 64]);
            g2lds16(Vp + (size_t)(si * 8 + (lane >> 3)) * Nv + key0 + (lane & 7) * 8,
                    &Vsh[si * 8 * 64]);
        }
        // bias: 16 instrs (4/wave), each 4 q-rows x 64 slots (u32)
#pragma unroll
        for (int s = 0; s < 4; s++) {
            int si = wave * 4 + s;
            g2lds16(Bp + (size_t)(si * 4 + (lane >> 4)) * Nv + key0 + (lane & 15) * 4,
                    &Bsh[si * 4 * 64]);
        }
        __syncthreads();

        // scores + exp + P for 2 chunks of 32 keys
#pragma unroll
        for (int c = 0; c < 2; c++) {
            s16x8 k0a = *(const s16x8*)&Ksh[(c * 32 + n_lo) * 64 + quad * 8];
            s16x8 k0b = *(const s16x8*)&Ksh[(c * 32 + n_lo) * 64 + 32 + quad * 8];
            s16x8 k1a = *(const s16x8*)&Ksh[(c * 32 + 16 + n_lo) * 64 + quad * 8];
            s16x8 k1b = *(const s16x8*)&Ksh[(c * 32 + 16 + n_lo) * 64 + 32 + quad * 8];
            f32x4 z = {0.f, 0.f, 0.f, 0.f};
            f32x4 s0 = __builtin_amdgcn_mfma_f32_16x16x32_bf16(
                a1, k0b, __builtin_amdgcn_mfma_f32_16x16x32_bf16(a0, k0a, z, 0, 0, 0), 0, 0, 0);
            f32x4 s1 = __builtin_amdgcn_mfma_f32_16x16x32_bf16(
                a1, k1b, __builtin_amdgcn_mfma_f32_16x16x32_bf16(a0, k1a, z, 0, 0, 0), 0, 0, 0);
#pragma unroll
            for (int i = 0; i < 4; i++) {
                int row = quad * 4 + i;
                uint2 u = *(const uint2*)&Bsh[(wave * 16 + row) * 64 + c * 32 + n_lo * 2];
                float e0 = __expf(fminf(s0[i] * 0.125f + __uint_as_float(u.x << 16), 60.f));
                float e1 = __expf(fminf(s1[i] * 0.125f + __uint_as_float(u.y << 16), 60.f));
                lacc[i] += e0 + e1;
                Pw[row * 72 + c * 32 + n_lo]      = f2bf(e0 * __uint_as_float(u.x & 0xFFFF0000u));
                Pw[row * 72 + c * 32 + 16 + n_lo] = f2bf(e1 * __uint_as_float(u.y & 0xFFFF0000u));
            }
        }

        // PV from LDS
#pragma unroll
        for (int c = 0; c < 2; c++) {
            s16x8 pa = *(const s16x8*)&Pw[n_lo * 72 + c * 32 + quad * 8];
#pragma unroll
            for (int t = 0; t < 4; t++) {
                s16x8 vb = *(const s16x8*)&Vsh[(t * 16 + n_lo) * 64 + c * 32 + quad * 8];
                O[t] = __builtin_amdgcn_mfma_f32_16x16x32_bf16(pa, vb, O[t], 0, 0, 0);
            }
        }
    }

    // l: sum partials across the 16 lanes sharing a row
#pragma unroll
    for (int i = 0; i < 4; i++)
#pragma unroll
        for (int off = 1; off < 16; off <<= 1) lacc[i] += __shfl_xor(lacc[i], off);

    float inv[4];
#pragma unroll
    for (int i = 0; i < 4; i++) inv[i] = 1.f / lacc[i];
#pragma unroll
    for (int t = 0; t < 4; t++)
#pragma unroll
        for (int i = 0; i < 4; i++) {
            float o = O[t][i] * inv[i];
            o = o > 0.f ? o : 0.01f * o;
            attn_l[((size_t)(b * Nv + qw + quad * 4 + i)) * DM + h * DHv + t * 16 + n_lo] = f2bf(o);
        }
}

// ---------------------------------------------------------------------------
extern "C" void kernel_launch(void* const* d_in, const int* in_sizes, int n_in,
                              void* d_out, int out_size, void* d_ws, size_t ws_size,
                              hipStream_t stream)
{
    const float* Z     = (const float*)d_in[0];
    const float* D     = (const float*)d_in[1];
    const float* nmsk  = (const float*)d_in[2];
    const float* msk   = (const float*)d_in[3];
    const float* Wqkv  = (const float*)d_in[4];
    const float* bqkv  = (const float*)d_in[5];
    const float* Wo    = (const float*)d_in[6];
    const float* g1    = (const float*)d_in[7];
    const float* b1    = (const float*)d_in[8];
    const float* g2    = (const float*)d_in[9];
    const float* b2    = (const float*)d_in[10];
    const float* Wp1   = (const float*)d_in[11];
    const float* bp1   = (const float*)d_in[12];
    const float* Wp2   = (const float*)d_in[13];
    const float* bp2   = (const float*)d_in[14];
    const float* gamma = (const float*)d_in[15];
    float* out = (float*)d_out;
    char* w = (char*)d_ws;

    const size_t MB = 1048576;
    short*    WqkvB = (short*)(w);
    short*    WoB   = (short*)(w + 1572864);
    short*    Wp1B  = (short*)(w + 2 * MB);
    short*    Wp2B  = (short*)(w + 4 * MB);
    float*    Z2    = (float*)(w + 6 * MB);
    uint32_t* Bm    = (uint32_t*)(w + 14 * MB);
    short*    Zn    = (short*)(w + 30 * MB);
    short*    Qb    = (short*)(w + 34 * MB);
    short*    Kb    = (short*)(w + 38 * MB);
    short*    VtB   = (short*)(w + 42 * MB);
    short*    AtnL  = (short*)(w + 30 * MB);
    short*    Zn2   = (short*)(w + 14 * MB);
    short*    Hb    = (short*)(w + 18 * MB);
    short*    Pp    = (short*)(w + 34 * MB);

    conv_all<<<3072, 256, 0, stream>>>(Wqkv, Wo, Wp1, Wp2, WqkvB, WoB, Wp1B, Wp2B);
    prep_bm2<<<4096, 256, 0, stream>>>(D, nmsk, msk, gamma, Bm);
    ln_kernel<<<TOKc, 256, 0, stream>>>(Z, g1, b1, Zn);
    gemm_bf16<0, 128, 64><<<dim3(24, 32), 256, 0, stream>>>(
        Zn, WqkvB, bqkv, nullptr, VtB, Qb, Kb, TOKc, 1536, 512, 512);
    attn_mfma<<<dim3(512), 256, 0, stream>>>(Qb, Kb, VtB, Bm, AtnL);
    gemm_bf16<1, 64, 64><<<dim3(8, 64), 256, 0, stream>>>(
        AtnL, WoB, nullptr, Z, Z2, nullptr, nullptr, TOKc, 512, 512, 512);
    ln_kernel<<<TOKc, 256, 0, stream>>>(Z2, g2, b2, Zn2);
    gemm_bf16<2, 128, 64><<<dim3(32, 32), 256, 0, stream>>>(
        Zn2, Wp1B, bp1, nullptr, Hb, nullptr, nullptr, TOKc, 2048, 512, 512);
    gemm_bf16<4, 128, 64><<<dim3(8, 32, 2), 256, 0, stream>>>(
        Hb, Wp2B, nullptr, nullptr, Pp, nullptr, nullptr, TOKc, 512, 1024, 2048);
    combine_mlp2<<<2048, 256, 0, stream>>>(Pp, bp2, Z2, out);
}